// Round 9
// baseline (595.505 us; speedup 1.0000x reference)
//
#include <hip/hip_runtime.h>
#include <hip/hip_bf16.h>
#include <stdint.h>

// Capsule routing, f32 in/out. B=32, Nin=2048, Din=16, Nout=64, Dout=32, 3 iters.
// Round 8: MFMA formulation. Per i: D[jd,b] = W_i[16x32k] * x_i^T[32k x 16b]
// via mfma_f32_16x16x32_bf16 with K zero-padded (lanes 32-63 = zero frags).
// One block = (16-i chunk, 16-batch group); phases: A logits(all i) -> B softmax
// -> C weighted accumulate; sacc and v-regs live in disjoint phases (<=~110 VGPR).

#define CB    32
#define NIN   2048
#define DIN   16
#define NOUT  64
#define DOUT  32
#define IPB   16                     // i's per block
#define NCB   (NIN / IPB)            // 128 chunk-blocks
#define WI    (NOUT * DOUT * DIN)    // 32768 elements per i
#define WELEM ((size_t)NIN * WI)     // 67,108,864

typedef __attribute__((ext_vector_type(8))) short bf16x8;
typedef __attribute__((ext_vector_type(4))) float f32x4;

static __device__ __forceinline__ uint32_t pack_bf2(float a, float b) {
    __hip_bfloat162 h = __float22bfloat162_rn(make_float2(a, b));
    uint32_t u; __builtin_memcpy(&u, &h, 4); return u;
}

// ---------------- W f32 -> bf16 transcode (pure streaming) ----------------
__global__ __launch_bounds__(256) void transcode(
    const float* __restrict__ W, uint32_t* __restrict__ Wb)
{
    const size_t stride = (size_t)gridDim.x * 256;
    for (size_t q = (size_t)blockIdx.x * 256 + threadIdx.x; q < WELEM / 8; q += stride) {
        const float4 a = *(const float4*)(W + q * 8);
        const float4 b = *(const float4*)(W + q * 8 + 4);
        uint4 o;
        o.x = pack_bf2(a.x, a.y); o.y = pack_bf2(a.z, a.w);
        o.z = pack_bf2(b.x, b.y); o.w = pack_bf2(b.z, b.w);
        *(uint4*)(Wb + q * 4) = o;
    }
}

// ---------------- MFMA routing pass ----------------
// grid 256: p -> chunk cb = (p>>4)*8 + (p&7) (both bg of a chunk on one XCD),
// bg = (p>>3)&1, b0 = bg*16. 512 threads = 8 waves; wave w owns j in [w*8, w*8+8).
// Dynamic LDS: IT>0: c[16][64][17] f32 (69632) + x[16][16][16] bf16 (8192); t aliases c.
//              IT=0: t (34816) + x (8192).
template <int IT>
__global__ __launch_bounds__(512, 2) void caps_mfma(
    const float* __restrict__ x, const uint16_t* __restrict__ Wh,
    const float* __restrict__ v_prev, const float* __restrict__ blog_in,
    float* __restrict__ blog_out, float* __restrict__ s_partial)
{
    extern __shared__ char smem[];
    constexpr size_t C_OFF = 0;
    constexpr size_t X_OFF = (IT > 0) ? 69632 : 34816;
    float*    c_lds = (float*)(smem + C_OFF);      // [16][64][17] (IT>0)
    uint16_t* x_lds = (uint16_t*)(smem + X_OFF);   // [16][16][16] bf16
    float*    t_lds = (float*)smem;                // [512][17] transpose (aliases c)

    const int p  = blockIdx.x;
    const int cb = (p >> 4) * 8 + (p & 7);
    const int bg = (p >> 3) & 1;
    const int b0 = bg * 16;
    const int t  = threadIdx.x;
    const int w  = t >> 6, l = t & 63;
    const bool lo32 = (l < 32);
    const int lb = l & 15;          // b (N) / jd-low (M) index
    const int lg = l >> 4;          // k-group / row-group

    // ---- stage x -> bf16 LDS [i][b][k] ----
    for (int q = t; q < IPB * 16 * 16 / 4; q += 512) {     // 1024 quads
        const int i = q >> 6, b = (q >> 2) & 15, k4 = (q & 3) * 4;
        const float4 xv = *(const float4*)(x + ((size_t)(b0 + b) * NIN + cb * IPB + i) * DIN + k4);
        uint2 uu;
        uu.x = pack_bf2(xv.x, xv.y);
        uu.y = pack_bf2(xv.z, xv.w);
        *(uint2*)&x_lds[(i * 16 + b) * 16 + k4] = uu;
    }
    __syncthreads();

    const f32x4  zacc  = {0.f, 0.f, 0.f, 0.f};
    const bf16x8 zfrag = {0, 0, 0, 0, 0, 0, 0, 0};

    if (IT > 0) {
        // v for this lane: v[b=lb][j = w*8+jj][d = lg*4 + r (+16)], f32
        float4 vlo[8], vhi[8];
#pragma unroll
        for (int jj = 0; jj < 8; ++jj) {
            const float* vp = v_prev + ((size_t)(b0 + lb) * NOUT + (w * 8 + jj)) * DOUT + lg * 4;
            vlo[jj] = *(const float4*)vp;
            vhi[jj] = *(const float4*)(vp + 16);
        }

        // ============ PHASE A: logits for all 16 i (no barriers) ============
#pragma unroll 1
        for (int ii = 0; ii < IPB; ++ii) {
            const int ig = cb * IPB + ii;
            bf16x8 bfr = zfrag;
            if (lo32) bfr = *(const bf16x8*)&x_lds[(ii * 16 + lb) * 16 + lg * 8];
            const uint16_t* wbase = Wh + (size_t)ig * WI;
#pragma unroll
            for (int jj = 0; jj < 8; ++jj) {
                const int jd0 = (w * 8 + jj) * 32;
                bf16x8 a0 = zfrag, a1 = zfrag;
                if (lo32) {
                    a0 = *(const bf16x8*)(wbase + (size_t)(jd0 + lb) * 16 + lg * 8);
                    a1 = *(const bf16x8*)(wbase + (size_t)(jd0 + 16 + lb) * 16 + lg * 8);
                }
                f32x4 d0 = __builtin_amdgcn_mfma_f32_16x16x32_bf16(a0, bfr, zacc, 0, 0, 0);
                f32x4 d1 = __builtin_amdgcn_mfma_f32_16x16x32_bf16(a1, bfr, zacc, 0, 0, 0);
                float pl = d0[0]*vlo[jj].x + d0[1]*vlo[jj].y + d0[2]*vlo[jj].z + d0[3]*vlo[jj].w
                         + d1[0]*vhi[jj].x + d1[1]*vhi[jj].y + d1[2]*vhi[jj].z + d1[3]*vhi[jj].w;
                pl += __shfl_xor(pl, 16);
                pl += __shfl_xor(pl, 32);
                if (l < 16) c_lds[(ii * 64 + w * 8 + jj) * 17 + l] = pl;
            }
        }
        __syncthreads();

        // ============ PHASE B: softmax over j, 256 rows (i,b) ============
#pragma unroll 1
        for (int q = 0; q < 32; ++q) {
            const int row = w * 32 + q;
            const int ii = row >> 4, b = row & 15;
            const int ig = cb * IPB + ii;
            float bl = c_lds[(ii * 64 + l) * 17 + b];
            if (IT == 2) bl += blog_in[((size_t)(b0 + b) * NIN + ig) * NOUT + l];
            if (IT == 1) blog_out[((size_t)(b0 + b) * NIN + ig) * NOUT + l] = bl;
            float m = bl;
#pragma unroll
            for (int o = 32; o; o >>= 1) m = fmaxf(m, __shfl_xor(m, o));
            const float e = __expf(bl - m);
            float s = e;
#pragma unroll
            for (int o = 32; o; o >>= 1) s += __shfl_xor(s, o);
            c_lds[(ii * 64 + l) * 17 + b] = e / s;
        }
        __syncthreads();
    }

    // ============ PHASE C: accumulate c * u_hat ============
    f32x4 sacc[16];
#pragma unroll
    for (int m = 0; m < 16; ++m) sacc[m] = zacc;

#pragma unroll 1
    for (int ii = 0; ii < IPB; ++ii) {
        const int ig = cb * IPB + ii;
        bf16x8 bfr = zfrag;
        if (lo32) bfr = *(const bf16x8*)&x_lds[(ii * 16 + lb) * 16 + lg * 8];
        const uint16_t* wbase = Wh + (size_t)ig * WI;
#pragma unroll
        for (int m = 0; m < 16; ++m) {
            const int jd0 = (w * 8 + (m >> 1)) * 32 + (m & 1) * 16;
            bf16x8 a0 = zfrag;
            if (lo32) a0 = *(const bf16x8*)(wbase + (size_t)(jd0 + lb) * 16 + lg * 8);
            f32x4 d = __builtin_amdgcn_mfma_f32_16x16x32_bf16(a0, bfr, zacc, 0, 0, 0);
            const float cv = (IT == 0) ? (1.0f / 64.0f)
                                       : c_lds[(ii * 64 + w * 8 + (m >> 1)) * 17 + lb];
#pragma unroll
            for (int r = 0; r < 4; ++r) sacc[m][r] += cv * d[r];
        }
    }
    __syncthreads();   // c_lds dead; t_lds (alias) safe to write

    // ============ transpose-store via LDS: spart[cb][b][jd], coalesced ============
#pragma unroll 1
    for (int part = 0; part < 4; ++part) {
        if ((w >> 1) == part) {
            const int wl = w & 1;
#pragma unroll
            for (int m = 0; m < 16; ++m) {
                const int jdl = wl * 256 + (m >> 1) * 32 + (m & 1) * 16 + lg * 4;
#pragma unroll
                for (int r = 0; r < 4; ++r)
                    t_lds[(jdl + r) * 17 + lb] = sacc[m][r];
            }
        }
        __syncthreads();
        {
            const int b = t >> 5, j0 = t & 31;
            float* dst = s_partial + ((size_t)cb * CB + b0 + b) * 2048 + part * 512;
#pragma unroll
            for (int q = 0; q < 16; ++q)
                dst[j0 + q * 32] = t_lds[(j0 + q * 32) * 17 + b];
        }
        __syncthreads();
    }
}

// ---------------- Reduce partials over chunk-blocks, add bias, squash ----------------
// s_partial layout: [cb 128][b 32][jd 2048]. One wave per (b,j).
__global__ __launch_bounds__(64) void caps_squash(
    const float* __restrict__ s_partial,
    const float* __restrict__ bias,       // [NOUT, DOUT]
    float* __restrict__ v_out)            // [B, NOUT, DOUT]
{
    const int bj = blockIdx.x;
    const int b  = bj / NOUT;
    const int j  = bj % NOUT;
    const int t  = threadIdx.x;
    const int d  = t & 31;
    const int h  = t >> 5;

    float sv = 0.f;
    for (int c = h; c < NCB; c += 2)
        sv += s_partial[((size_t)c * CB + b) * 2048 + j * DOUT + d];
    sv += __shfl_xor(sv, 32);
    sv += bias[j * DOUT + d];

    float sq = sv * sv;
#pragma unroll
    for (int o = 16; o; o >>= 1) sq += __shfl_xor(sq, o);

    float scale = (sq / (1.0f + sq)) * rsqrtf(sq + 1e-9f);
    float v = scale * sv;
    if (t < 32) v_out[((size_t)b * NOUT + j) * DOUT + d] = v;
}

extern "C" void kernel_launch(void* const* d_in, const int* in_sizes, int n_in,
                              void* d_out, int out_size, void* d_ws, size_t ws_size,
                              hipStream_t stream) {
    const float* x    = (const float*)d_in[0];
    const float* W    = (const float*)d_in[1];
    const float* bias = (const float*)d_in[2];
    float* out = (float*)d_out;

    const size_t wh_bytes = WELEM * 2;                       // 134,217,728
    const size_t nblog    = (size_t)CB * NIN * NOUT;         // 4,194,304 f
    const size_t nspart   = (size_t)NCB * CB * 2048;         // 8,388,608 f
    char* base = (char*)d_ws;
    uint16_t* Wh = (uint16_t*)base;
    float* blog  = (float*)(base + wh_bytes);
    float* spart = blog + nblog;
    float* vbuf  = spart + nspart;
    (void)ws_size;  // requires ~185MB; harness has provided >= this in all prior rounds

    const int SM0 = 34816 + 8192;   // IT=0: t_lds + x_lds
    const int SM1 = 69632 + 8192;   // IT>0: c_lds (t aliases) + x_lds

    hipFuncSetAttribute(reinterpret_cast<const void*>(caps_mfma<0>),
                        hipFuncAttributeMaxDynamicSharedMemorySize, SM0);
    hipFuncSetAttribute(reinterpret_cast<const void*>(caps_mfma<1>),
                        hipFuncAttributeMaxDynamicSharedMemorySize, SM1);
    hipFuncSetAttribute(reinterpret_cast<const void*>(caps_mfma<2>),
                        hipFuncAttributeMaxDynamicSharedMemorySize, SM1);

    transcode<<<2048, 256, 0, stream>>>(W, (uint32_t*)Wh);

    caps_mfma<0><<<256, 512, SM0, stream>>>(x, Wh, nullptr, nullptr, nullptr, spart);
    caps_squash<<<CB * NOUT, 64, 0, stream>>>(spart, bias, vbuf);

    caps_mfma<1><<<256, 512, SM1, stream>>>(x, Wh, vbuf, nullptr, blog, spart);
    caps_squash<<<CB * NOUT, 64, 0, stream>>>(spart, bias, vbuf);

    caps_mfma<2><<<256, 512, SM1, stream>>>(x, Wh, vbuf, blog, nullptr, spart);
    caps_squash<<<CB * NOUT, 64, 0, stream>>>(spart, bias, out);
}

// Round 10
// 249.989 us; speedup vs baseline: 2.3821x; 2.3821x over previous
//
#include <hip/hip_runtime.h>
#include <hip/hip_bf16.h>
#include <stdint.h>

// Capsule routing, f32 in/out. B=32, Nin=2048, Din=16, Nout=64, Dout=32, 3 iters.
// Round 10: mfma_f32_32x32x16_bf16 (K=16=Din exact, no zero-pad; M=32 d-rows of
// one j; N=32 = ALL batches -> zero cross-block W sharing). Per-i {logits ->
// softmax -> weighted accumulate} with W_i L2-hot for the re-read. Pass0 fuses
// the f32->bf16 W transcode. 1024-thr blocks (16 waves, <=128 VGPR), spart bf16.

#define CB    32
#define NIN   2048
#define DIN   16
#define NOUT  64
#define DOUT  32
#define IPB   8
#define NCB   (NIN / IPB)            // 256 blocks, 1/CU
#define WI    (NOUT * DOUT * DIN)    // 32768 elements per i
#define WELEM ((size_t)NIN * WI)

typedef __attribute__((ext_vector_type(8)))  short bf16x8;
typedef __attribute__((ext_vector_type(16))) float f32x16;
typedef _Float16 h2 __attribute__((ext_vector_type(2)));

// LDS layout (bytes): IT>0: [v 135168][c 8448][x 10240] = 153856; IT0: [x 10240]
#define VOFF 0
#define COFF 135168
#define XOFF_IT 143616
#define SMEM_IT  153856
#define SMEM_P0  10240

static __device__ __forceinline__ uint32_t pack_bf2(float a, float b) {
    __hip_bfloat162 hh = __float22bfloat162_rn(make_float2(a, b));
    uint32_t u; __builtin_memcpy(&u, &hh, 4); return u;
}
static __device__ __forceinline__ uint16_t f2bf(float v) {
    return (uint16_t)(pack_bf2(v, 0.f) & 0xffffu);
}
static __device__ __forceinline__ float bf2f(uint16_t u) {
    uint32_t v = (uint32_t)u << 16; float f; __builtin_memcpy(&f, &v, 4); return f;
}
static __device__ __forceinline__ uint32_t pack_h2(float a, float b) {
    h2 r; r.x = (_Float16)a; r.y = (_Float16)b;
    uint32_t u; __builtin_memcpy(&u, &r, 4); return u;
}
static __device__ __forceinline__ h2 as_h2(uint32_t u) {
    h2 r; __builtin_memcpy(&r, &u, 4); return r;
}

// ---------------- routing pass ----------------
// Block cb owns i in [cb*8, cb*8+8), ALL 32 batches. 16 waves; wave w owns
// j in [w*4, w*4+4). Lane: bl = l&31 (= b for B/D cols, = jd-row for A), h = l>>5.
// A-frag: W[i][j*32+bl][k=8h..8h+8)   B-frag: x[bl][i][k=8h..8h+8)
// D (verified C/D layout): col b = l&31, row d = (reg&3)+8*(reg>>2)+4h.
template <int IT>
__global__ __launch_bounds__(1024, 4) void caps_pass(
    const float* __restrict__ x, const void* __restrict__ Wv,
    uint32_t* __restrict__ WhOut,
    const float* __restrict__ v_prev, const float* __restrict__ blog_in,
    float* __restrict__ blog_out, uint16_t* __restrict__ s_partial)
{
    extern __shared__ char smem[];
    uint32_t* v_lds = (uint32_t*)(smem + VOFF);                  // [64j*16dp][33b] h2
    float*    c_lds = (float*)(smem + COFF);                     // [64j][33b]
    uint32_t* x_lds = (uint32_t*)(smem + (IT > 0 ? XOFF_IT : 0)); // [8i*32b][10] k-pairs

    const int cb = blockIdx.x;
    const int t  = threadIdx.x;
    const int w  = t >> 6, l = t & 63;
    const int bl = l & 31, h = l >> 5;
    const int j0 = w * 4;

    // ---- stage x -> bf16 pairs (coalesced: consecutive t = consecutive k4,i) ----
    {
        const int b = t >> 5, i = (t >> 2) & 7, k4 = (t & 3) * 4;
        const float4 xv = *(const float4*)(x + ((size_t)b * NIN + cb * IPB + i) * DIN + k4);
        x_lds[(i * 32 + b) * 10 + (k4 >> 1)]     = pack_bf2(xv.x, xv.y);
        x_lds[(i * 32 + b) * 10 + (k4 >> 1) + 1] = pack_bf2(xv.z, xv.w);
    }
    if (IT > 0) {
        // ---- stage v -> f16 pairs [j][dp][33+b] (coalesced reads, conflict-free writes) ----
#pragma unroll 4
        for (int rep = 0; rep < 32; ++rep) {
            const int idx = rep * 1024 + t;
            const int b = idx >> 10, j = (idx >> 4) & 63, dp = idx & 15;
            const float2 vv = *(const float2*)(v_prev + ((size_t)b * NOUT + j) * DOUT + dp * 2);
            v_lds[(j * 16 + dp) * 33 + b] = pack_h2(vv.x, vv.y);
        }
    }
    __syncthreads();

    f32x16 sacc[4];
#pragma unroll
    for (int jj = 0; jj < 4; ++jj) sacc[jj] = (f32x16)0.0f;

    const uint16_t* Wb = (const uint16_t*)Wv;
    const float*    Wf = (const float*)Wv;
    constexpr int base_dp[8] = {0, 1, 4, 5, 8, 9, 12, 13};

#pragma unroll 1
    for (int i = 0; i < IPB; ++i) {
        const int ig = cb * IPB + i;
        const size_t wbase = (size_t)ig * WI;

        // B-frag (reused across j): x[bl][i][8h..8h+8)
        bf16x8 bfr;
        {
            uint32_t uu[4];
            const uint32_t* xp = &x_lds[(i * 32 + bl) * 10 + h * 4];
            uu[0] = xp[0]; uu[1] = xp[1]; uu[2] = xp[2]; uu[3] = xp[3];
            __builtin_memcpy(&bfr, uu, 16);
        }

        if (IT > 0) {
            // ===== PHASE A: logits for this wave's 4 j =====
#pragma unroll
            for (int jj = 0; jj < 4; ++jj) {
                const int j = j0 + jj;
                const bf16x8 afr = *(const bf16x8*)(Wb + wbase + (size_t)(j * 32 + bl) * 16 + h * 8);
                const f32x16 D = __builtin_amdgcn_mfma_f32_32x32x16_bf16(afr, bfr, (f32x16)0.0f, 0, 0, 0);
                float acc = 0.f;
#pragma unroll
                for (int rp = 0; rp < 8; ++rp) {
                    const int dp = base_dp[rp] + 2 * h;
                    h2 dpk; dpk.x = (_Float16)D[2 * rp]; dpk.y = (_Float16)D[2 * rp + 1];
                    acc = __builtin_amdgcn_fdot2(dpk, as_h2(v_lds[(j * 16 + dp) * 33 + bl]), acc, false);
                }
                acc += __shfl_xor(acc, 32);       // combine d-halves
                if (h == 0) c_lds[j * 33 + bl] = acc;
            }
            __syncthreads();

            // ===== PHASE B: softmax over j (32 b-rows, 2 per wave) =====
#pragma unroll
            for (int rr = 0; rr < 2; ++rr) {
                const int b = w * 2 + rr;
                float bv = c_lds[l * 33 + b];
                if (IT == 2) bv += blog_in[((size_t)b * NIN + ig) * NOUT + l];
                if (IT == 1) blog_out[((size_t)b * NIN + ig) * NOUT + l] = bv;
                float m = bv;
#pragma unroll
                for (int o = 32; o; o >>= 1) m = fmaxf(m, __shfl_xor(m, o));
                const float e = __expf(bv - m);
                float s = e;
#pragma unroll
                for (int o = 32; o; o >>= 1) s += __shfl_xor(s, o);
                c_lds[l * 33 + b] = e / s;
            }
            __syncthreads();
        }

        // ===== PHASE C: accumulate =====
#pragma unroll
        for (int jj = 0; jj < 4; ++jj) {
            const int j = j0 + jj;
            if (IT == 0) {
                // f32 W -> bf16 frag + emit Wh (fused transcode)
                const float4* wp = (const float4*)(Wf + wbase + (size_t)(j * 32 + bl) * 16 + h * 8);
                const float4 a4 = wp[0], b4 = wp[1];
                uint32_t uu[4];
                uu[0] = pack_bf2(a4.x, a4.y); uu[1] = pack_bf2(a4.z, a4.w);
                uu[2] = pack_bf2(b4.x, b4.y); uu[3] = pack_bf2(b4.z, b4.w);
                bf16x8 afr; __builtin_memcpy(&afr, uu, 16);
                uint4 st; st.x = uu[0]; st.y = uu[1]; st.z = uu[2]; st.w = uu[3];
                *(uint4*)(WhOut + ((wbase + (size_t)(j * 32 + bl) * 16 + h * 8) >> 1)) = st;
                sacc[jj] = __builtin_amdgcn_mfma_f32_32x32x16_bf16(afr, bfr, sacc[jj], 0, 0, 0);
            } else {
                const bf16x8 afr = *(const bf16x8*)(Wb + wbase + (size_t)(j * 32 + bl) * 16 + h * 8);
                const f32x16 D = __builtin_amdgcn_mfma_f32_32x32x16_bf16(afr, bfr, (f32x16)0.0f, 0, 0, 0);
                const float cv = c_lds[j * 33 + bl];      // c[b,i,j]: d-invariant
                sacc[jj] += D * cv;
            }
        }
        if (IT > 0) __syncthreads();   // protect c_lds before next i's phase A
    }

    // ---- store partials: spart[cb][jd][b] bf16 ----
    const float cscale = (IT == 0) ? (1.0f / 64.0f) : 1.0f;
#pragma unroll
    for (int jj = 0; jj < 4; ++jj) {
        const int j = j0 + jj;
#pragma unroll
        for (int r = 0; r < 16; ++r) {
            const int d = (r & 3) + 8 * (r >> 2) + 4 * h;
            s_partial[(size_t)cb * (2048 * 32) + (size_t)(j * 32 + d) * 32 + bl] =
                f2bf(sacc[jj][r] * cscale);
        }
    }
}

// ---------------- reduce over cb + bias + squash ----------------
// grid 256 = (j, b-octet); 256 thr: d = t>>3, blq = t&7.
__global__ __launch_bounds__(256) void caps_squash(
    const uint16_t* __restrict__ sp, const float* __restrict__ bias,
    float* __restrict__ vout)
{
    const int j  = blockIdx.x >> 2;
    const int bq = blockIdx.x & 3;
    const int t  = threadIdx.x;
    const int d  = t >> 3;
    const int blq = t & 7;
    const int b  = bq * 8 + blq;

    const uint16_t* p = sp + (size_t)(j * 32 + d) * 32 + b;
    float s0 = 0.f, s1 = 0.f, s2 = 0.f, s3 = 0.f;
#pragma unroll 4
    for (int c = 0; c < NCB; c += 4) {
        s0 += bf2f(p[(size_t)(c + 0) * (2048 * 32)]);
        s1 += bf2f(p[(size_t)(c + 1) * (2048 * 32)]);
        s2 += bf2f(p[(size_t)(c + 2) * (2048 * 32)]);
        s3 += bf2f(p[(size_t)(c + 3) * (2048 * 32)]);
    }
    const float sv = ((s0 + s1) + (s2 + s3)) + bias[j * DOUT + d];

    float sq = sv * sv;
    sq += __shfl_xor(sq, 8);    // d within-wave octet reduce (same blq)
    sq += __shfl_xor(sq, 16);
    sq += __shfl_xor(sq, 32);

    __shared__ float sh[4][8];
    if ((t & 63) < 8) sh[t >> 6][t & 7] = sq;
    __syncthreads();
    const float tot = sh[0][blq] + sh[1][blq] + sh[2][blq] + sh[3][blq];
    const float scale = (tot / (1.0f + tot)) * rsqrtf(tot + 1e-9f);
    vout[(size_t)b * (NOUT * DOUT) + j * DOUT + d] = scale * sv;
}

extern "C" void kernel_launch(void* const* d_in, const int* in_sizes, int n_in,
                              void* d_out, int out_size, void* d_ws, size_t ws_size,
                              hipStream_t stream) {
    const float* x    = (const float*)d_in[0];
    const float* W    = (const float*)d_in[1];
    const float* bias = (const float*)d_in[2];
    float* out = (float*)d_out;

    // ws: Wh 134.22MB | blog 16.78MB | spart(bf16) 33.55MB | vbuf 0.26MB = 184.8MB
    char* base = (char*)d_ws;
    uint32_t* Wh    = (uint32_t*)base;
    float*    blog  = (float*)(base + WELEM * 2);
    uint16_t* spart = (uint16_t*)(base + WELEM * 2 + (size_t)CB * NIN * NOUT * 4);
    float*    vbuf  = (float*)(base + WELEM * 2 + (size_t)CB * NIN * NOUT * 4
                               + (size_t)NCB * 2048 * 32 * 2);
    (void)ws_size;

    hipFuncSetAttribute(reinterpret_cast<const void*>(caps_pass<0>),
                        hipFuncAttributeMaxDynamicSharedMemorySize, SMEM_P0);
    hipFuncSetAttribute(reinterpret_cast<const void*>(caps_pass<1>),
                        hipFuncAttributeMaxDynamicSharedMemorySize, SMEM_IT);
    hipFuncSetAttribute(reinterpret_cast<const void*>(caps_pass<2>),
                        hipFuncAttributeMaxDynamicSharedMemorySize, SMEM_IT);

    caps_pass<0><<<NCB, 1024, SMEM_P0, stream>>>(x, W, Wh, nullptr, nullptr, nullptr, spart);
    caps_squash<<<NOUT * 4, 256, 0, stream>>>(spart, bias, vbuf);

    caps_pass<1><<<NCB, 1024, SMEM_IT, stream>>>(x, Wh, nullptr, vbuf, nullptr, blog, spart);
    caps_squash<<<NOUT * 4, 256, 0, stream>>>(spart, bias, vbuf);

    caps_pass<2><<<NCB, 1024, SMEM_IT, stream>>>(x, Wh, nullptr, vbuf, blog, nullptr, spart);
    caps_squash<<<NOUT * 4, 256, 0, stream>>>(spart, bias, out);
}

// Round 11
// 249.161 us; speedup vs baseline: 2.3900x; 1.0033x over previous
//
#include <hip/hip_runtime.h>
#include <hip/hip_bf16.h>
#include <stdint.h>

// Capsule routing, f32 in/out. B=32, Nin=2048, Din=16, Nout=64, Dout=32, 3 iters.
// Round 10: mfma_f32_32x32x16_bf16 (K=16=Din exact, no zero-pad; M=32 d-rows of
// one j; N=32 = ALL batches -> zero cross-block W sharing). Per-i {logits ->
// softmax -> weighted accumulate} with W_i L2-hot for the re-read. Pass0 fuses
// the f32->bf16 W transcode. 1024-thr blocks (16 waves, <=128 VGPR), spart bf16.

#define CB    32
#define NIN   2048
#define DIN   16
#define NOUT  64
#define DOUT  32
#define IPB   8
#define NCB   (NIN / IPB)            // 256 blocks, 1/CU
#define WI    (NOUT * DOUT * DIN)    // 32768 elements per i
#define WELEM ((size_t)NIN * WI)

typedef __attribute__((ext_vector_type(8)))  short bf16x8;
typedef __attribute__((ext_vector_type(16))) float f32x16;
typedef _Float16 h2 __attribute__((ext_vector_type(2)));

// LDS layout (bytes): IT>0: [v 135168][c 8448][x 10240] = 153856; IT0: [x 10240]
#define VOFF 0
#define COFF 135168
#define XOFF_IT 143616
#define SMEM_IT  153856
#define SMEM_P0  10240

static __device__ __forceinline__ uint32_t pack_bf2(float a, float b) {
    __hip_bfloat162 hh = __float22bfloat162_rn(make_float2(a, b));
    uint32_t u; __builtin_memcpy(&u, &hh, 4); return u;
}
static __device__ __forceinline__ uint16_t f2bf(float v) {
    return (uint16_t)(pack_bf2(v, 0.f) & 0xffffu);
}
static __device__ __forceinline__ float bf2f(uint16_t u) {
    uint32_t v = (uint32_t)u << 16; float f; __builtin_memcpy(&f, &v, 4); return f;
}
static __device__ __forceinline__ uint32_t pack_h2(float a, float b) {
    h2 r; r.x = (_Float16)a; r.y = (_Float16)b;
    uint32_t u; __builtin_memcpy(&u, &r, 4); return u;
}
static __device__ __forceinline__ h2 as_h2(uint32_t u) {
    h2 r; __builtin_memcpy(&r, &u, 4); return r;
}

// ---------------- routing pass ----------------
// Block cb owns i in [cb*8, cb*8+8), ALL 32 batches. 16 waves; wave w owns
// j in [w*4, w*4+4). Lane: bl = l&31 (= b for B/D cols, = jd-row for A), h = l>>5.
// A-frag: W[i][j*32+bl][k=8h..8h+8)   B-frag: x[bl][i][k=8h..8h+8)
// D (verified C/D layout): col b = l&31, row d = (reg&3)+8*(reg>>2)+4h.
template <int IT>
__global__ __launch_bounds__(1024, 4) void caps_pass(
    const float* __restrict__ x, const void* __restrict__ Wv,
    uint32_t* __restrict__ WhOut,
    const float* __restrict__ v_prev, const float* __restrict__ blog_in,
    float* __restrict__ blog_out, uint16_t* __restrict__ s_partial)
{
    extern __shared__ char smem[];
    uint32_t* v_lds = (uint32_t*)(smem + VOFF);                  // [64j*16dp][33b] h2
    float*    c_lds = (float*)(smem + COFF);                     // [64j][33b]
    uint32_t* x_lds = (uint32_t*)(smem + (IT > 0 ? XOFF_IT : 0)); // [8i*32b][10] k-pairs

    const int cb = blockIdx.x;
    const int t  = threadIdx.x;
    const int w  = t >> 6, l = t & 63;
    const int bl = l & 31, h = l >> 5;
    const int j0 = w * 4;

    // ---- stage x -> bf16 pairs (coalesced: consecutive t = consecutive k4,i) ----
    {
        const int b = t >> 5, i = (t >> 2) & 7, k4 = (t & 3) * 4;
        const float4 xv = *(const float4*)(x + ((size_t)b * NIN + cb * IPB + i) * DIN + k4);
        x_lds[(i * 32 + b) * 10 + (k4 >> 1)]     = pack_bf2(xv.x, xv.y);
        x_lds[(i * 32 + b) * 10 + (k4 >> 1) + 1] = pack_bf2(xv.z, xv.w);
    }
    if (IT > 0) {
        // ---- stage v -> f16 pairs [j][dp][33+b] (coalesced reads, conflict-free writes) ----
#pragma unroll 4
        for (int rep = 0; rep < 32; ++rep) {
            const int idx = rep * 1024 + t;
            const int b = idx >> 10, j = (idx >> 4) & 63, dp = idx & 15;
            const float2 vv = *(const float2*)(v_prev + ((size_t)b * NOUT + j) * DOUT + dp * 2);
            v_lds[(j * 16 + dp) * 33 + b] = pack_h2(vv.x, vv.y);
        }
    }
    __syncthreads();

    f32x16 sacc[4];
#pragma unroll
    for (int jj = 0; jj < 4; ++jj) sacc[jj] = (f32x16)0.0f;

    const uint16_t* Wb = (const uint16_t*)Wv;
    const float*    Wf = (const float*)Wv;
    constexpr int base_dp[8] = {0, 1, 4, 5, 8, 9, 12, 13};

#pragma unroll 1
    for (int i = 0; i < IPB; ++i) {
        const int ig = cb * IPB + i;
        const size_t wbase = (size_t)ig * WI;

        // B-frag (reused across j): x[bl][i][8h..8h+8)
        bf16x8 bfr;
        {
            uint32_t uu[4];
            const uint32_t* xp = &x_lds[(i * 32 + bl) * 10 + h * 4];
            uu[0] = xp[0]; uu[1] = xp[1]; uu[2] = xp[2]; uu[3] = xp[3];
            __builtin_memcpy(&bfr, uu, 16);
        }

        if (IT > 0) {
            // ===== PHASE A: logits for this wave's 4 j =====
#pragma unroll
            for (int jj = 0; jj < 4; ++jj) {
                const int j = j0 + jj;
                const bf16x8 afr = *(const bf16x8*)(Wb + wbase + (size_t)(j * 32 + bl) * 16 + h * 8);
                const f32x16 D = __builtin_amdgcn_mfma_f32_32x32x16_bf16(afr, bfr, (f32x16)0.0f, 0, 0, 0);
                float acc = 0.f;
#pragma unroll
                for (int rp = 0; rp < 8; ++rp) {
                    const int dp = base_dp[rp] + 2 * h;
                    h2 dpk; dpk.x = (_Float16)D[2 * rp]; dpk.y = (_Float16)D[2 * rp + 1];
                    acc = __builtin_amdgcn_fdot2(dpk, as_h2(v_lds[(j * 16 + dp) * 33 + bl]), acc, false);
                }
                acc += __shfl_xor(acc, 32);       // combine d-halves
                if (h == 0) c_lds[j * 33 + bl] = acc;
            }
            __syncthreads();

            // ===== PHASE B: softmax over j (32 b-rows, 2 per wave) =====
#pragma unroll
            for (int rr = 0; rr < 2; ++rr) {
                const int b = w * 2 + rr;
                float bv = c_lds[l * 33 + b];
                if (IT == 2) bv += blog_in[((size_t)b * NIN + ig) * NOUT + l];
                if (IT == 1) blog_out[((size_t)b * NIN + ig) * NOUT + l] = bv;
                float m = bv;
#pragma unroll
                for (int o = 32; o; o >>= 1) m = fmaxf(m, __shfl_xor(m, o));
                const float e = __expf(bv - m);
                float s = e;
#pragma unroll
                for (int o = 32; o; o >>= 1) s += __shfl_xor(s, o);
                c_lds[l * 33 + b] = e / s;
            }
            __syncthreads();
        }

        // ===== PHASE C: accumulate =====
#pragma unroll
        for (int jj = 0; jj < 4; ++jj) {
            const int j = j0 + jj;
            if (IT == 0) {
                // f32 W -> bf16 frag + emit Wh (fused transcode)
                const float4* wp = (const float4*)(Wf + wbase + (size_t)(j * 32 + bl) * 16 + h * 8);
                const float4 a4 = wp[0], b4 = wp[1];
                uint32_t uu[4];
                uu[0] = pack_bf2(a4.x, a4.y); uu[1] = pack_bf2(a4.z, a4.w);
                uu[2] = pack_bf2(b4.x, b4.y); uu[3] = pack_bf2(b4.z, b4.w);
                bf16x8 afr; __builtin_memcpy(&afr, uu, 16);
                uint4 st; st.x = uu[0]; st.y = uu[1]; st.z = uu[2]; st.w = uu[3];
                *(uint4*)(WhOut + ((wbase + (size_t)(j * 32 + bl) * 16 + h * 8) >> 1)) = st;
                sacc[jj] = __builtin_amdgcn_mfma_f32_32x32x16_bf16(afr, bfr, sacc[jj], 0, 0, 0);
            } else {
                const bf16x8 afr = *(const bf16x8*)(Wb + wbase + (size_t)(j * 32 + bl) * 16 + h * 8);
                const f32x16 D = __builtin_amdgcn_mfma_f32_32x32x16_bf16(afr, bfr, (f32x16)0.0f, 0, 0, 0);
                const float cv = c_lds[j * 33 + bl];      // c[b,i,j]: d-invariant
                sacc[jj] += D * cv;
            }
        }
        if (IT > 0) __syncthreads();   // protect c_lds before next i's phase A
    }

    // ---- store partials: spart[cb][jd][b] bf16 ----
    const float cscale = (IT == 0) ? (1.0f / 64.0f) : 1.0f;
#pragma unroll
    for (int jj = 0; jj < 4; ++jj) {
        const int j = j0 + jj;
#pragma unroll
        for (int r = 0; r < 16; ++r) {
            const int d = (r & 3) + 8 * (r >> 2) + 4 * h;
            s_partial[(size_t)cb * (2048 * 32) + (size_t)(j * 32 + d) * 32 + bl] =
                f2bf(sacc[jj][r] * cscale);
        }
    }
}

// ---------------- reduce over cb + bias + squash ----------------
// grid 256 = (j, b-octet); 256 thr: d = t>>3, blq = t&7.
__global__ __launch_bounds__(256) void caps_squash(
    const uint16_t* __restrict__ sp, const float* __restrict__ bias,
    float* __restrict__ vout)
{
    const int j  = blockIdx.x >> 2;
    const int bq = blockIdx.x & 3;
    const int t  = threadIdx.x;
    const int d  = t >> 3;
    const int blq = t & 7;
    const int b  = bq * 8 + blq;

    const uint16_t* p = sp + (size_t)(j * 32 + d) * 32 + b;
    float s0 = 0.f, s1 = 0.f, s2 = 0.f, s3 = 0.f;
#pragma unroll 4
    for (int c = 0; c < NCB; c += 4) {
        s0 += bf2f(p[(size_t)(c + 0) * (2048 * 32)]);
        s1 += bf2f(p[(size_t)(c + 1) * (2048 * 32)]);
        s2 += bf2f(p[(size_t)(c + 2) * (2048 * 32)]);
        s3 += bf2f(p[(size_t)(c + 3) * (2048 * 32)]);
    }
    const float sv = ((s0 + s1) + (s2 + s3)) + bias[j * DOUT + d];

    float sq = sv * sv;
    sq += __shfl_xor(sq, 8);    // d within-wave octet reduce (same blq)
    sq += __shfl_xor(sq, 16);
    sq += __shfl_xor(sq, 32);

    __shared__ float sh[4][8];
    if ((t & 63) < 8) sh[t >> 6][t & 7] = sq;
    __syncthreads();
    const float tot = sh[0][blq] + sh[1][blq] + sh[2][blq] + sh[3][blq];
    const float scale = (tot / (1.0f + tot)) * rsqrtf(tot + 1e-9f);
    vout[(size_t)b * (NOUT * DOUT) + j * DOUT + d] = scale * sv;
}

extern "C" void kernel_launch(void* const* d_in, const int* in_sizes, int n_in,
                              void* d_out, int out_size, void* d_ws, size_t ws_size,
                              hipStream_t stream) {
    const float* x    = (const float*)d_in[0];
    const float* W    = (const float*)d_in[1];
    const float* bias = (const float*)d_in[2];
    float* out = (float*)d_out;

    // ws: Wh 134.22MB | blog 16.78MB | spart(bf16) 33.55MB | vbuf 0.26MB = 184.8MB
    char* base = (char*)d_ws;
    uint32_t* Wh    = (uint32_t*)base;
    float*    blog  = (float*)(base + WELEM * 2);
    uint16_t* spart = (uint16_t*)(base + WELEM * 2 + (size_t)CB * NIN * NOUT * 4);
    float*    vbuf  = (float*)(base + WELEM * 2 + (size_t)CB * NIN * NOUT * 4
                               + (size_t)NCB * 2048 * 32 * 2);
    (void)ws_size;

    hipFuncSetAttribute(reinterpret_cast<const void*>(caps_pass<0>),
                        hipFuncAttributeMaxDynamicSharedMemorySize, SMEM_P0);
    hipFuncSetAttribute(reinterpret_cast<const void*>(caps_pass<1>),
                        hipFuncAttributeMaxDynamicSharedMemorySize, SMEM_IT);
    hipFuncSetAttribute(reinterpret_cast<const void*>(caps_pass<2>),
                        hipFuncAttributeMaxDynamicSharedMemorySize, SMEM_IT);

    caps_pass<0><<<NCB, 1024, SMEM_P0, stream>>>(x, W, Wh, nullptr, nullptr, nullptr, spart);
    caps_squash<<<NOUT * 4, 256, 0, stream>>>(spart, bias, vbuf);

    caps_pass<1><<<NCB, 1024, SMEM_IT, stream>>>(x, Wh, nullptr, vbuf, nullptr, blog, spart);
    caps_squash<<<NOUT * 4, 256, 0, stream>>>(spart, bias, vbuf);

    caps_pass<2><<<NCB, 1024, SMEM_IT, stream>>>(x, Wh, nullptr, vbuf, blog, nullptr, spart);
    caps_squash<<<NOUT * 4, 256, 0, stream>>>(spart, bias, out);
}